// Round 1
// 263.714 us; speedup vs baseline: 1.0295x; 1.0295x over previous
//
#include <hip/hip_runtime.h>

// ---------- 32x128 tiled GEMM body, 256 threads, 4x4 reg tile ----------
// C[m0+m, col0+n] = sum_k A[(m0+m)*lda + k] * B[k*ldb + col0 + n]
// smem: 16*36 + 16*132 = 2688 floats.
__device__ __forceinline__ void gemm32(
    float* __restrict__ smem,
    const float* __restrict__ A, int lda,
    const float* __restrict__ B, int ldb,
    float* __restrict__ C, int ldc, int K,
    int m0, int col0) {
  float* As = smem;            // [16][36] (k-major, transposed)
  float* Bs = smem + 16 * 36;  // [16][132]
  const int t = threadIdx.x;
  const int tn = t & 31, tm = t >> 5;
  const int lam = t >> 2, lak = (t & 3) * 4;   // threads 0..127 load A
  const int lbk = t >> 4, lbn = (t & 15) * 8;
  float acc[4][4];
#pragma unroll
  for (int i = 0; i < 4; ++i)
#pragma unroll
    for (int j = 0; j < 4; ++j) acc[i][j] = 0.f;
  for (int k0 = 0; k0 < K; k0 += 16) {
    if (t < 128) {
      float4 av = *reinterpret_cast<const float4*>(A + (size_t)(m0 + lam) * lda + k0 + lak);
      As[(lak + 0) * 36 + lam] = av.x;
      As[(lak + 1) * 36 + lam] = av.y;
      As[(lak + 2) * 36 + lam] = av.z;
      As[(lak + 3) * 36 + lam] = av.w;
    }
    const float* bp = B + (size_t)(k0 + lbk) * ldb + col0 + lbn;
    float4 b0 = *reinterpret_cast<const float4*>(bp);
    float4 b1 = *reinterpret_cast<const float4*>(bp + 4);
    float* bd = &Bs[lbk * 132 + lbn];
    *reinterpret_cast<float4*>(bd) = b0;
    *reinterpret_cast<float4*>(bd + 4) = b1;
    __syncthreads();
#pragma unroll
    for (int kk = 0; kk < 16; ++kk) {
      float4 a4 = *reinterpret_cast<const float4*>(&As[kk * 36 + tm * 4]);
      float4 b4 = *reinterpret_cast<const float4*>(&Bs[kk * 132 + tn * 4]);
      float a[4] = {a4.x, a4.y, a4.z, a4.w};
      float b[4] = {b4.x, b4.y, b4.z, b4.w};
#pragma unroll
      for (int i = 0; i < 4; ++i)
#pragma unroll
        for (int j = 0; j < 4; ++j) acc[i][j] = fmaf(a[i], b[j], acc[i][j]);
    }
    __syncthreads();
  }
#pragma unroll
  for (int i = 0; i < 4; ++i) {
    float* cp = C + (size_t)(m0 + tm * 4 + i) * ldc + col0 + tn * 4;
    *reinterpret_cast<float4*>(cp) =
        make_float4(acc[i][0], acc[i][1], acc[i][2], acc[i][3]);
  }
}

// ======================= GAT attention body (compile-time E) ==================
// Phase 1: load rows + per-head dot + full in-wave butterfly reduce.
// Phase 2: wave-parallel softmax (64 lanes over e-axis).
// Phase 3: float2 aggregation, all 256 threads.
// smem floats: MR*FIN + MR*PP + E*4.
template <int FIN, int TPR, int E>
__device__ __forceinline__ void gat_body(
    float* __restrict__ smem,
    const float* __restrict__ xself, const float* __restrict__ xneigh,
    const float* __restrict__ waS, const float* __restrict__ waN,
    float* __restrict__ out) {
  constexpr int MR = E + 1;
  constexpr int RPP = 256 / TPR;
  constexpr int PP = (TPR > 64) ? 8 : 4;  // partials per row (4 floats per 64-lane span)
  float* tile = smem;                 // MR*FIN
  float* partial = tile + MR * FIN;   // MR*PP
  float* alpha = partial + MR * PP;   // E*4
  const int t = threadIdx.x;
  const int el = t / TPR;
  const int f0 = (t % TPR) * 4;
  float4 wn[4], ws[4];
#pragma unroll
  for (int h = 0; h < 4; ++h) {
    wn[h] = *reinterpret_cast<const float4*>(waN + h * FIN + f0);
    ws[h] = *reinterpret_cast<const float4*>(waS + h * FIN + f0);
  }
#pragma unroll
  for (int p = 0; p * RPP < MR; ++p) {
    int e = p * RPP + el;
    if (e < MR) {
      const float* src = (e < E) ? (xneigh + (size_t)e * FIN + f0) : (xself + f0);
      float4 x = *reinterpret_cast<const float4*>(src);
      *reinterpret_cast<float4*>(tile + e * FIN + f0) = x;
      float ph[4];
#pragma unroll
      for (int h = 0; h < 4; ++h) {
        float4 w = (e < E) ? wn[h] : ws[h];
        ph[h] = x.x * w.x + x.y * w.y + x.z * w.z + x.w * w.w;
      }
#pragma unroll
      for (int h = 0; h < 4; ++h) {  // butterfly over the row's lane span
        ph[h] += __shfl_xor(ph[h], 1);
        ph[h] += __shfl_xor(ph[h], 2);
        ph[h] += __shfl_xor(ph[h], 4);
        ph[h] += __shfl_xor(ph[h], 8);
        ph[h] += __shfl_xor(ph[h], 16);
        if constexpr (TPR > 64) ph[h] += __shfl_xor(ph[h], 32);
      }
      if constexpr (TPR <= 64) {
        if ((t & (TPR - 1)) == 0)
          *reinterpret_cast<float4*>(partial + e * 4) =
              make_float4(ph[0], ph[1], ph[2], ph[3]);
      } else {
        if ((t & 63) == 0) {
          int half = (t >> 6) & 1;
          *reinterpret_cast<float4*>(partial + e * 8 + half * 4) =
              make_float4(ph[0], ph[1], ph[2], ph[3]);
        }
      }
    }
  }
  __syncthreads();
  if (t < 64) {  // wave-parallel softmax over E neighbors x 4 heads
    const int h = t & 3;
    const int e0 = t >> 2;  // 0..15
    float selfl = partial[E * PP + h];
    if constexpr (PP == 8) selfl += partial[E * PP + 4 + h];
    float x0 = -1e30f, x1 = -1e30f;
    if (e0 < E) {
      float v = partial[e0 * PP + h];
      if constexpr (PP == 8) v += partial[e0 * PP + 4 + h];
      float x = selfl + v;
      x0 = (x > 0.f) ? x : 0.2f * x;  // LeakyReLU(0.2)
    }
    if constexpr (E > 16) {
      if (e0 + 16 < E) {
        float v = partial[(e0 + 16) * PP + h];
        if constexpr (PP == 8) v += partial[(e0 + 16) * PP + 4 + h];
        float x = selfl + v;
        x1 = (x > 0.f) ? x : 0.2f * x;
      }
    }
    float m = fmaxf(x0, x1);
    m = fmaxf(m, __shfl_xor(m, 4));
    m = fmaxf(m, __shfl_xor(m, 8));
    m = fmaxf(m, __shfl_xor(m, 16));
    m = fmaxf(m, __shfl_xor(m, 32));
    float p0 = (e0 < E) ? __expf(x0 - m) : 0.f;
    float p1 = 0.f;
    if constexpr (E > 16) p1 = (e0 + 16 < E) ? __expf(x1 - m) : 0.f;
    float s = p0 + p1;
    s += __shfl_xor(s, 4);
    s += __shfl_xor(s, 8);
    s += __shfl_xor(s, 16);
    s += __shfl_xor(s, 32);
    float inv = 1.f / s;
    if (e0 < E) alpha[e0 * 4 + h] = p0 * inv;
    if constexpr (E > 16)
      if (e0 + 16 < E) alpha[(e0 + 16) * 4 + h] = p1 * inv;
  }
  __syncthreads();
  constexpr int C2 = FIN / 2;  // float2 chunks per head
  for (int o = t; o < 4 * C2; o += 256) {
    int h = o / C2, f = (o % C2) * 2;
    float2 acc = make_float2(0.f, 0.f);
#pragma unroll
    for (int e = 0; e < E; ++e) {
      float a = alpha[e * 4 + h];
      float2 x = *reinterpret_cast<const float2*>(tile + e * FIN + f);
      acc.x = fmaf(a, x.x, acc.x);
      acc.y = fmaf(a, x.y, acc.y);
    }
    *reinterpret_cast<float2*>(out + h * FIN + f) = acc;
  }
}

// ======================= prepA: wa vectors + T = W1_hblk @ Wfc_hblk ===========
// blocks [0,128): T gemm (4 heads x 16 mb x 2 nb, 32-row tiles); [128,148): wa.
__global__ void __launch_bounds__(256) prepA(
    const float* __restrict__ W0, const float* __restrict__ a0s,
    const float* __restrict__ a0n,
    const float* __restrict__ W1, const float* __restrict__ a1s,
    const float* __restrict__ a1n, const float* __restrict__ Wfc,
    float* __restrict__ wa0s, float* __restrict__ wa0n,
    float* __restrict__ wa1s, float* __restrict__ wa1n,
    float* __restrict__ T) {
  __shared__ float smem[2688];
  const int b = blockIdx.x;
  if (b < 128) {
    // T[h][k][o] = sum_m W1[k, h*128+m] * Wfc[h*128+m, o]; M=512,K=128,N=256
    int h = b >> 5, mb = (b >> 1) & 15, nb = b & 1;
    gemm32(smem, W1 + h * 128, 512, Wfc + (size_t)h * 32768, 256,
           T + (size_t)h * 131072, 256, 128, mb * 32, nb * 128);
    return;
  }
  int idx = (b - 128) * 256 + threadIdx.x;
  if (idx >= 5120) return;
  const float* W; const float* a; float* dst; int i; int FIN;
  if (idx < 512)       { W = W0; a = a0s; dst = wa0s; i = idx;        FIN = 128; }
  else if (idx < 1024) { W = W0; a = a0n; dst = wa0n; i = idx - 512;  FIN = 128; }
  else if (idx < 3072) { W = W1; a = a1s; dst = wa1s; i = idx - 1024; FIN = 512; }
  else                 { W = W1; a = a1n; dst = wa1n; i = idx - 3072; FIN = 512; }
  int f = i >> 2, h = i & 3;
  const float* wrow = W + (size_t)f * 512 + h * 128;
  const float* arow = a + h * 128;
  float v = 0.f;
#pragma unroll 8
  for (int d = 0; d < 128; ++d) v = fmaf(wrow[d], arow[d], v);
  dst[h * FIN + f] = v;
}

// ==== fusedB: Wfinal gemm (128) + va (16) FIRST, then layer-0 attn (11264) ====
// gemm/va have no dependency on attention -> front of grid so they overlap the
// attention stream instead of forming a serial tail.
__global__ void __launch_bounds__(256) fusedB(
    const float* __restrict__ h0, const float* __restrict__ h1,
    const float* __restrict__ h2, const float* __restrict__ wa0s,
    const float* __restrict__ wa0n, float* __restrict__ xagg,
    const float* __restrict__ W0, const float* __restrict__ wa1s,
    const float* __restrict__ wa1n, const float* __restrict__ T,
    float* __restrict__ va1s, float* __restrict__ va1n,
    float* __restrict__ Wfinal) {
  __shared__ float smem[3532];  // max(attn E=25: 3532, gemm: 2688)
  const int b = blockIdx.x;
  if (b < 128) {
    // Wfinal[h][(h0b*128+f)][o] = sum_n W0[f, h0b*128+n] * T[h][h0b*128+n][o]
    int h = b >> 5, h0b = (b >> 3) & 3, mb = (b >> 1) & 3, nb = b & 1;
    gemm32(smem, W0 + h0b * 128, 512,
           T + (size_t)h * 131072 + (size_t)h0b * 32768, 256,
           Wfinal + (size_t)h * 131072 + (size_t)h0b * 32768, 256, 128,
           mb * 32, nb * 128);
    return;
  }
  if (b < 144) {
    // va1: va[h*512 + h0b*128 + f] = sum_n W0[f, h0b*128+n] * wa1[h*512+h0b*128+n]
    int idx = (b - 128) * 256 + threadIdx.x;  // exactly 4096
    const float* wa = (idx < 2048) ? wa1s : wa1n;
    float* dst = (idx < 2048) ? va1s : va1n;
    int i = idx & 2047;
    int h = i >> 9, h0b = (i >> 7) & 3, f = i & 127;
    const float* w0row = W0 + (size_t)f * 512 + h0b * 128;
    const float* warow = wa + h * 512 + h0b * 128;
    float v = 0.f;
#pragma unroll 8
    for (int n = 0; n < 128; ++n) v = fmaf(w0row[n], warow[n], v);
    dst[i] = v;
    return;
  }
  if (b < 144 + 1024) {
    int n = b - 144;
    gat_body<128, 32, 10>(smem, h0 + (size_t)n * 128, h1 + (size_t)n * 1280,
                          wa0s, wa0n, xagg + (size_t)n * 512);
    return;
  }
  int g = b - 1168;
  gat_body<128, 32, 25>(smem, h1 + (size_t)g * 128, h2 + (size_t)g * 3200,
                        wa0s, wa0n, xagg + (size_t)(1024 + g) * 512);
}

// ======================= layer 1 on xagg space ================================
__global__ void __launch_bounds__(256) gat_layer1(
    const float* __restrict__ xagg, const float* __restrict__ vaS,
    const float* __restrict__ vaN, float* __restrict__ aggx) {
  __shared__ float smem[5760];  // 11*512 + 11*8 + 40
  const int b = blockIdx.x;
  gat_body<512, 128, 10>(smem, xagg + (size_t)b * 512,
                         xagg + (size_t)(1024 + b * 10) * 512, vaS, vaN,
                         aggx + (size_t)b * 2048);
}

// ======================= tail: K-split GEMM + reduce ==========================
__global__ void __launch_bounds__(256) gemm_ksplit(
    const float* __restrict__ A, const float* __restrict__ B,
    float* __restrict__ Cpart) {
  __shared__ float smem[2688];
  const int ks = blockIdx.z;
  gemm32(smem, A + ks * 256, 2048, B + (size_t)ks * 65536, 256,
         Cpart + (size_t)ks * 262144, 256, 256, blockIdx.x * 32,
         blockIdx.y * 128);
}

__global__ void __launch_bounds__(256) reduce8(
    const float* __restrict__ Cpart, float* __restrict__ out) {
  int i = blockIdx.x * 256 + threadIdx.x;  // float4 index, 65536 total
  const float4* p = reinterpret_cast<const float4*>(Cpart) + i;
  float4 s = p[0];
#pragma unroll
  for (int ks = 1; ks < 8; ++ks) {
    float4 v = p[(size_t)ks * 65536];
    s.x += v.x; s.y += v.y; s.z += v.z; s.w += v.w;
  }
  reinterpret_cast<float4*>(out)[i] = s;
}

extern "C" void kernel_launch(void* const* d_in, const int* in_sizes, int n_in,
                              void* d_out, int out_size, void* d_ws, size_t ws_size,
                              hipStream_t stream) {
  const float* h0  = (const float*)d_in[0];
  const float* h1  = (const float*)d_in[1];
  const float* h2  = (const float*)d_in[2];
  const float* W0  = (const float*)d_in[3];
  const float* a0s = (const float*)d_in[4];
  const float* a0n = (const float*)d_in[5];
  const float* W1  = (const float*)d_in[6];
  const float* a1s = (const float*)d_in[7];
  const float* a1n = (const float*)d_in[8];
  const float* Wfc = (const float*)d_in[9];
  float* out = (float*)d_out;

  float* ws = (float*)d_ws;
  float* wa0s   = ws;                    // [4][128]
  float* wa0n   = wa0s + 512;            // [4][128]
  float* wa1s   = wa0n + 512;            // [4][512]
  float* wa1n   = wa1s + 2048;           // [4][512]
  float* va1s   = wa1n + 2048;           // [4][4][128]
  float* va1n   = va1s + 2048;           // [4][4][128]
  float* T      = va1n + 2048;           // [4][512][256] = 524288
  float* Wfinal = T + 524288;            // [4][512][256] = 524288
  float* xaggA  = Wfinal + 524288;       // [11264][512]  = 5767168
  float* aggx   = xaggA + 11264 * 512;   // [1024][2048]  = 2097152
  float* Cpart  = aggx + 2097152;        // [8][1024][256]= 2097152

  // P1: wa vectors + T (32-row tiles, 148 blocks)
  prepA<<<148, 256, 0, stream>>>(W0, a0s, a0n, W1, a1s, a1n, Wfc,
                                 wa0s, wa0n, wa1s, wa1n, T);
  // Wfinal gemm + va FIRST (overlap), then layer-0 attention (both levels)
  fusedB<<<11408, 256, 0, stream>>>(h0, h1, h2, wa0s, wa0n, xaggA,
                                    W0, wa1s, wa1n, T, va1s, va1n, Wfinal);
  // Layer 1 directly in xagg space
  gat_layer1<<<1024, 256, 0, stream>>>(xaggA, va1s, va1n, aggx);
  // Final: out = aggx[1024,2048] @ Wfinal[2048,256], 32-row tiles, K-split x8
  gemm_ksplit<<<dim3(32, 2, 8), 256, 0, stream>>>(aggx, Wfinal, Cpart);
  reduce8<<<256, 256, 0, stream>>>(Cpart, out);
}